// Round 7
// baseline (307.096 us; speedup 1.0000x reference)
//
#include <hip/hip_runtime.h>
#include <math.h>

// GQA block. Round 7: split-K=2 GEMMs (atomicAdd fp32 epilogue, memset init),
// attention 64q/128-thread blocks (4 blocks/CU), permuted-V b128 PV frags.
// Shapes: B=2, T=2048, DIM=1024, H=16, HKV=4, HD=64.

#define B_   2
#define T_   2048
#define DIM_ 1024
#define NH   16
#define NKV  4
#define HD_  64
#define BT_  (B_ * T_)

typedef _Float16 half8_t __attribute__((ext_vector_type(8)));
typedef _Float16 half4_t __attribute__((ext_vector_type(4)));
typedef float    f32x4   __attribute__((ext_vector_type(4)));

__device__ __forceinline__ void async_copy16(_Float16* lds, const _Float16* g) {
    __builtin_amdgcn_global_load_lds(
        (const __attribute__((address_space(1))) void*)g,
        (__attribute__((address_space(3))) void*)lds, 16, 0, 0);
}

// ---------------------------------------------------------------------------
// Kernel 0: RoPE sincos table: tab[t*32+i] = (cos, sin)(t * 10000^(-i/32))
// ---------------------------------------------------------------------------
__global__ __launch_bounds__(256) void tab_kernel(float2* __restrict__ tab)
{
    int gid = blockIdx.x * 256 + threadIdx.x;   // 0..65535
    int t = gid >> 5, i = gid & 31;
    double invf = pow(10000.0, -(double)i / 32.0);
    double ang  = (double)t * invf;
    tab[gid] = make_float2((float)cos(ang), (float)sin(ang));
}

// ---------------------------------------------------------------------------
// Kernel 1: weight prep (validated r3-r6). fp32 W rows (2560: Wq|Wk|Wv|Wo) ->
// fp16 hi/lo planes, MFMA-fragment-swizzled chunks:
// c = ((nb*32+kb)*4 + k8)*128 + nl  holds  W[nb*128+nl][kb*32+k8*8 .. +8]
// ---------------------------------------------------------------------------
__global__ __launch_bounds__(256) void prep_w_kernel(
    const float* __restrict__ Wq, const float* __restrict__ Wk,
    const float* __restrict__ Wv, const float* __restrict__ Wo,
    _Float16* __restrict__ Whi, _Float16* __restrict__ Wlo)
{
    int c = blockIdx.x * 256 + threadIdx.x;       // 0..327679
    int nl = c & 127, k8 = (c >> 7) & 3, kb = (c >> 9) & 31, nb = c >> 14;
    int n = nb * 128 + nl, k = kb * 32 + k8 * 8;
    const float* src;
    if (n < 1024)      src = Wq + (size_t)n * 1024;
    else if (n < 1280) src = Wk + (size_t)(n - 1024) * 1024;
    else if (n < 1536) src = Wv + (size_t)(n - 1280) * 1024;
    else               src = Wo + (size_t)(n - 1536) * 1024;
    float4 f0 = *(const float4*)(src + k);
    float4 f1 = *(const float4*)(src + k + 4);
    float xs[8] = {f0.x, f0.y, f0.z, f0.w, f1.x, f1.y, f1.z, f1.w};
    half8_t hi, lo;
#pragma unroll
    for (int j = 0; j < 8; ++j) {
        _Float16 h = (_Float16)xs[j];
        hi[j] = h;
        lo[j] = (_Float16)(xs[j] - (float)h);
    }
    *(half8_t*)&Whi[(size_t)c * 8] = hi;
    *(half8_t*)&Wlo[(size_t)c * 8] = lo;
}

// ---------------------------------------------------------------------------
// Kernel 2: A prep: hs fp32 [4096 x 1024] -> fp16 swizzled chunks
// [mb][kb][k8][ml]*8.
// ---------------------------------------------------------------------------
__global__ __launch_bounds__(256) void prep_a_kernel(
    const float* __restrict__ hs, _Float16* __restrict__ Ah)
{
    int gid = blockIdx.x * 256 + threadIdx.x;    // 0..524287
    int k8 = gid & 3, kb = (gid >> 2) & 31, ml = (gid >> 7) & 127, mb = gid >> 14;
    const float* src = hs + (size_t)(mb * 128 + ml) * 1024 + kb * 32 + k8 * 8;
    float4 f0 = *(const float4*)src;
    float4 f1 = *(const float4*)(src + 4);
    half8_t hv;
    hv[0] = (_Float16)f0.x; hv[1] = (_Float16)f0.y;
    hv[2] = (_Float16)f0.z; hv[3] = (_Float16)f0.w;
    hv[4] = (_Float16)f1.x; hv[5] = (_Float16)f1.y;
    hv[6] = (_Float16)f1.z; hv[7] = (_Float16)f1.w;
    size_t c = ((size_t)(mb * 32 + kb) * 4 + k8) * 128 + ml;
    *(half8_t*)&Ah[c * 8] = hv;
}

// ---------------------------------------------------------------------------
// Kernel 3: 2-pass MFMA GEMM, all-DMA staging, SPLIT-K=2 (blockIdx.z).
// Each split does 16 k-iters and atomicAdds into zero-initialized fp32 out.
// Bias added by split 0 only. MODE 0: QKV scatter. MODE 1: row-major.
// ---------------------------------------------------------------------------
template <int MODE>
__global__ __launch_bounds__(256, 3) void gemm2p_kernel(
    const _Float16* __restrict__ Ah,
    const _Float16* __restrict__ Whi, const _Float16* __restrict__ Wlo,
    int nb0,
    const float* __restrict__ bq, const float* __restrict__ bk,
    const float* __restrict__ bv,
    float* __restrict__ o0, float* __restrict__ o1, float* __restrict__ o2)
{
    __shared__ _Float16 sA [2][4096];
    __shared__ _Float16 sBh[2][4096];
    __shared__ _Float16 sBl[2][4096];

    const int tid  = threadIdx.x;
    const int w    = tid >> 6, lane = tid & 63;
    const int quad = lane >> 4, l15 = lane & 15;
    const int wm = w >> 1, wn = w & 1;
    const int mb   = blockIdx.y;
    const int nblk = blockIdx.x;
    const int ks   = blockIdx.z;
    const int kb0  = ks * 16;

    const _Float16* AB   = Ah  + (size_t)mb * 32 * 4096;
    const _Float16* WhiB = Whi + (size_t)(nb0 + nblk) * 32 * 4096;
    const _Float16* WloB = Wlo + (size_t)(nb0 + nblk) * 32 * 4096;

    f32x4 acc[4][4];
#pragma unroll
    for (int mt = 0; mt < 4; ++mt)
#pragma unroll
        for (int nt = 0; nt < 4; ++nt) {
            f32x4 z = {0.f, 0.f, 0.f, 0.f};
            acc[mt][nt] = z;
        }

#define GEMM_STAGE(buf, kbl)                                                  \
    {                                                                         \
        const _Float16* ga = AB   + (size_t)(kbl) * 4096;                     \
        const _Float16* gh = WhiB + (size_t)(kbl) * 4096;                     \
        const _Float16* gl = WloB + (size_t)(kbl) * 4096;                     \
        _Pragma("unroll")                                                     \
        for (int p = 0; p < 2; ++p) {                                         \
            int cb = p * 256 + w * 64;                                        \
            async_copy16(&sA [buf][cb * 8], ga + (size_t)(cb + lane) * 8);    \
            async_copy16(&sBh[buf][cb * 8], gh + (size_t)(cb + lane) * 8);    \
            async_copy16(&sBl[buf][cb * 8], gl + (size_t)(cb + lane) * 8);    \
        }                                                                     \
    }

    GEMM_STAGE(0, kb0);
    __syncthreads();

    for (int kb = 0; kb < 16; ++kb) {
        const int cur = kb & 1;
        if (kb + 1 < 16) { GEMM_STAGE(cur ^ 1, kb0 + kb + 1); }

        half8_t af[4], bf[4], blv[4];
#pragma unroll
        for (int mt = 0; mt < 4; ++mt) {
            int ch = quad * 128 + wm * 64 + mt * 16 + l15;
            af[mt] = *(const half8_t*)&sA[cur][ch * 8];
        }
#pragma unroll
        for (int nt = 0; nt < 4; ++nt) {
            int ch = quad * 128 + wn * 64 + nt * 16 + l15;
            bf[nt]  = *(const half8_t*)&sBh[cur][ch * 8];
            blv[nt] = *(const half8_t*)&sBl[cur][ch * 8];
        }
#pragma unroll
        for (int mt = 0; mt < 4; ++mt)
#pragma unroll
            for (int nt = 0; nt < 4; ++nt) {
                acc[mt][nt] = __builtin_amdgcn_mfma_f32_16x16x32_f16(af[mt], bf[nt],  acc[mt][nt], 0, 0, 0);
                acc[mt][nt] = __builtin_amdgcn_mfma_f32_16x16x32_f16(af[mt], blv[nt], acc[mt][nt], 0, 0, 0);
            }
        __syncthreads();
    }

    const int m0 = mb * 128;
    if constexpr (MODE == 0) {
        int nreg = nblk * 128;
        const float* bias; float* outp; int nh2, nbl;
        if (nreg < 1024)      { bias = bq; outp = o0; nh2 = NH;  nbl = nreg; }
        else if (nreg < 1280) { bias = bk; outp = o1; nh2 = NKV; nbl = nreg - 1024; }
        else                  { bias = bv; outp = o2; nh2 = NKV; nbl = nreg - 1280; }
        int hh = (nbl + wn * 64) >> 6;
#pragma unroll
        for (int mt = 0; mt < 4; ++mt)
#pragma unroll
            for (int r = 0; r < 4; ++r) {
                int m  = m0 + wm * 64 + mt * 16 + quad * 4 + r;
                int b_ = m >> 11, t_ = m & 2047;
                float* cp = outp + (((size_t)(b_ * nh2 + hh)) * T_ + t_) * 64;
#pragma unroll
                for (int nt = 0; nt < 4; ++nt) {
                    int dd = nt * 16 + l15;
                    float add = acc[mt][nt][r] + (ks == 0 ? bias[hh * 64 + dd] : 0.0f);
                    atomicAdd(&cp[dd], add);
                }
            }
    } else {
        int n0 = nblk * 128 + wn * 64;
#pragma unroll
        for (int mt = 0; mt < 4; ++mt)
#pragma unroll
            for (int r = 0; r < 4; ++r) {
                int m = m0 + wm * 64 + mt * 16 + quad * 4 + r;
#pragma unroll
                for (int nt = 0; nt < 4; ++nt) {
                    int n = n0 + nt * 16 + l15;
                    float add = acc[mt][nt][r] + (ks == 0 ? bq[n] : 0.0f);
                    atomicAdd(&o0[(size_t)m * 1024 + n], add);
                }
            }
    }
#undef GEMM_STAGE
}

// ---------------------------------------------------------------------------
// Kernel 4: RoPE via table, fp32 -> fp16 (q pre-scaled by 0.125).
// ---------------------------------------------------------------------------
__global__ __launch_bounds__(256) void rope_half_kernel(
    const float* __restrict__ qf, const float* __restrict__ kf,
    const float2* __restrict__ tab,
    _Float16* __restrict__ qh, _Float16* __restrict__ kh)
{
    int gid = blockIdx.x * 256 + threadIdx.x;
    int i   = gid & 31;
    int row = gid >> 5;
    const float* src; _Float16* dst; int t; float sc;
    if (row < B_ * NH * T_) {
        src = qf + (size_t)row * 64; dst = qh + (size_t)row * 64;
        t = row & (T_ - 1); sc = 0.125f;
    } else {
        int r = row - B_ * NH * T_;
        src = kf + (size_t)r * 64; dst = kh + (size_t)r * 64;
        t = r & (T_ - 1); sc = 1.0f;
    }
    float2 cs = tab[t * 32 + i];
    float c = cs.x, s = cs.y;
    float x0 = src[i], x1 = src[i + 32];
    float xe = src[2 * i], xo = src[2 * i + 1];
    dst[i]      = (_Float16)((x0 * c - xo * s) * sc);
    dst[i + 32] = (_Float16)((x1 * c + xe * s) * sc);
}

// ---------------------------------------------------------------------------
// Kernel 5: V transpose fp32 [b,hkv,t,d] -> fp16 [b,hkv,d,t'] with keys
// PERMUTED within each 64-key group: original k = 16t+4q+j stored at
// p = q*16 + t*4 + j, so a PV A-frag b128 covers a t-pair for one quad.
// ---------------------------------------------------------------------------
__global__ __launch_bounds__(256) void vtrans_kernel(
    const float* __restrict__ vf, _Float16* __restrict__ vth)
{
    __shared__ float ts[64][65];
    const int bhk = blockIdx.y;
    const int t0  = blockIdx.x * 64;
    const int tid = threadIdx.x;
    const float* src = vf + (size_t)bhk * T_ * 64 + (size_t)t0 * 64;

    int row = tid >> 2, c0 = (tid & 3) * 16;
#pragma unroll
    for (int j = 0; j < 16; ++j)
        ts[row][c0 + j] = src[(size_t)row * 64 + c0 + j];
    __syncthreads();

    int drow = tid >> 2;                  // d index 0..63
    int t4   = (c0 >> 4) * 4;             // t = c0/16
    _Float16* dstb = vth + (size_t)bhk * 64 * T_ + (size_t)drow * T_ + t0;
#pragma unroll
    for (int q = 0; q < 4; ++q) {
        half4_t hv;
#pragma unroll
        for (int j = 0; j < 4; ++j)
            hv[j] = (_Float16)ts[c0 + q * 4 + j][drow];
        *(half4_t*)&dstb[q * 16 + t4] = hv;
    }
}

// ---------------------------------------------------------------------------
// Kernel 6: flash attention. 64q/block, 128 threads (2 waves x 32q).
// S^T = K Q^T -> exp() -> P register-direct into 16x16x16 PV MFMAs.
// Fixed-max softmax (validated r5/r6). K/V dbuf via global_load_lds.
// K LDS chunk g*64 + t*16 + l  <-> K[key=16t+l][d=8g..+8]
// V LDS chunk g*64 + dt*16 + l <-> V^T[d=16dt+l][perm-pos 8g..+8]
//   (perm: piece g = 2*quad + u covers t-subtiles {2u, 2u+1} for that quad)
// ---------------------------------------------------------------------------
__global__ __launch_bounds__(128, 2) void attn_kernel(
    const _Float16* __restrict__ qh, const _Float16* __restrict__ kh,
    const _Float16* __restrict__ vth, _Float16* __restrict__ ctx_h)
{
    __shared__ _Float16 Ks[2][4096];
    __shared__ _Float16 Vs[2][4096];

    const int qt = blockIdx.x;          // 0..31 (64-q tiles)
    const int bh = blockIdx.y;          // 0..31
    const int b  = bh >> 4, h = bh & 15, hk = h >> 2;
    const int tid  = threadIdx.x;       // 0..127
    const int w    = tid >> 6;          // wave 0..1
    const int lane = tid & 63;
    const int quad = lane >> 4, l15 = lane & 15;

    // Q B-frags for 2 strips of 16 q-rows (q pre-scaled by 0.125 at rope)
    half8_t aq0[2], aq1[2];
#pragma unroll
    for (int s = 0; s < 2; ++s) {
        const _Float16* Qb = qh +
            ((size_t)(b * NH + h) * T_ + qt * 64 + w * 32 + s * 16 + l15) * 64 + quad * 8;
        aq0[s] = *(const half8_t*)(Qb);
        aq1[s] = *(const half8_t*)(Qb + 32);
    }

    const _Float16* Kb = kh  + (size_t)(b * NKV + hk) * (T_ * 64);
    const _Float16* Vb = vth + (size_t)(b * NKV + hk) * (64 * T_);

#define ATTN_STAGE(buf, ktile)                                                \
    {                                                                         \
        _Float16* kd = &Ks[buf][0];                                           \
        _Float16* vd = &Vs[buf][0];                                           \
        _Pragma("unroll")                                                     \
        for (int p = 0; p < 4; ++p) {                                         \
            int cb = p * 128 + w * 64;                                        \
            int c  = cb + lane;                                               \
            int l_ = c & 15, t_ = (c >> 4) & 3, g_ = c >> 6;                  \
            const _Float16* kg = Kb + ((size_t)((ktile) * 64 + t_ * 16 + l_)) * 64 + g_ * 8; \
            const _Float16* vg = Vb + ((size_t)(t_ * 16 + l_)) * T_ + (ktile) * 64 + g_ * 8; \
            async_copy16(kd + cb * 8, kg);                                    \
            async_copy16(vd + cb * 8, vg);                                    \
        }                                                                     \
    }

    float l_i[2] = {0.0f, 0.0f};
    f32x4 o_acc[2][4];
#pragma unroll
    for (int s = 0; s < 2; ++s)
#pragma unroll
        for (int dt = 0; dt < 4; ++dt) { f32x4 z = {0.f,0.f,0.f,0.f}; o_acc[s][dt] = z; }

    ATTN_STAGE(0, 0);
    __syncthreads();

    for (int kt = 0; kt < T_ / 64; ++kt) {
        const int cur = kt & 1;
        if (kt + 1 < T_ / 64) { ATTN_STAGE(cur ^ 1, kt + 1); }

        // K A-frags: chunk quad*64 + t*16 + l15 (d 8quad..), +256 chunks d+32
        half8_t ak0[4], ak1[4];
#pragma unroll
        for (int t = 0; t < 4; ++t) {
            const _Float16* kr = &Ks[cur][(quad * 64 + t * 16 + l15) * 8];
            ak0[t] = *(const half8_t*)(kr);
            ak1[t] = *(const half8_t*)(kr + 2048);
        }
        // V A-frags: b128 per (t-pair u, dt): chunk (2*quad+u)*64 + dt*16 + l15
        half8_t av8[2][4];
#pragma unroll
        for (int u = 0; u < 2; ++u)
#pragma unroll
            for (int dt = 0; dt < 4; ++dt)
                av8[u][dt] = *(const half8_t*)&Vs[cur][((2 * quad + u) * 64 + dt * 16 + l15) * 8];

#pragma unroll
        for (int s = 0; s < 2; ++s) {
            // S^T tiles: rows = keys (quad*4+r of subtile t), cols = q (l15)
            f32x4 sv[4];
#pragma unroll
            for (int t = 0; t < 4; ++t) {
                f32x4 z = {0.f,0.f,0.f,0.f};
                z     = __builtin_amdgcn_mfma_f32_16x16x32_f16(ak0[t], aq0[s], z, 0, 0, 0);
                sv[t] = __builtin_amdgcn_mfma_f32_16x16x32_f16(ak1[t], aq1[s], z, 0, 0, 0);
            }
#pragma unroll
            for (int t = 0; t < 4; ++t) {
                float p0 = __expf(sv[t][0]);
                float p1 = __expf(sv[t][1]);
                float p2 = __expf(sv[t][2]);
                float p3 = __expf(sv[t][3]);
                l_i[s] += (p0 + p1) + (p2 + p3);
                half4_t pb;
                pb[0] = (_Float16)p0; pb[1] = (_Float16)p1;
                pb[2] = (_Float16)p2; pb[3] = (_Float16)p3;
                int u = t >> 1, hf = (t & 1) * 4;
#pragma unroll
                for (int dt = 0; dt < 4; ++dt) {
                    half4_t a4;
                    a4[0] = av8[u][dt][hf + 0];
                    a4[1] = av8[u][dt][hf + 1];
                    a4[2] = av8[u][dt][hf + 2];
                    a4[3] = av8[u][dt][hf + 3];
                    o_acc[s][dt] = __builtin_amdgcn_mfma_f32_16x16x16f16(
                        a4, pb, o_acc[s][dt], 0, 0, 0);
                }
            }
        }
        __syncthreads();
    }

    // epilogue: reduce l across quads, normalize, store fp16 into swizzled
    // ctx chunks (O^T value at (quad,l15) = (d=16dt+4quad+r, q))
#pragma unroll
    for (int s = 0; s < 2; ++s) {
        float l = l_i[s];
        l += __shfl_xor(l, 16);
        l += __shfl_xor(l, 32);
        float inv = 1.0f / l;
        int row = qt * 64 + w * 32 + s * 16 + l15;   // 0..2047 within batch
        int mrow = b * 2048 + row;
        int mb = mrow >> 7, ml = mrow & 127;
#pragma unroll
        for (int dt = 0; dt < 4; ++dt)
#pragma unroll
            for (int r = 0; r < 4; ++r) {
                int d  = 16 * dt + 4 * quad + r;
                int kb = 2 * h + (d >> 5);
                int k8 = (d >> 3) & 3;
                int j  = d & 7;
                ctx_h[(((size_t)(mb * 32 + kb) * 4 + k8) * 128 + ml) * 8 + j] =
                    (_Float16)(o_acc[s][dt][r] * inv);
            }
    }
#undef ATTN_STAGE
}

// ---------------------------------------------------------------------------
extern "C" void kernel_launch(void* const* d_in, const int* in_sizes, int n_in,
                              void* d_out, int out_size, void* d_ws, size_t ws_size,
                              hipStream_t stream)
{
    const float* hs = (const float*)d_in[0];
    const float* Wq = (const float*)d_in[1];
    const float* bq = (const float*)d_in[2];
    const float* Wk = (const float*)d_in[3];
    const float* bk = (const float*)d_in[4];
    const float* Wv = (const float*)d_in[5];
    const float* bv = (const float*)d_in[6];
    const float* Wo = (const float*)d_in[7];
    const float* bo = (const float*)d_in[8];
    float* out = (float*)d_out;

    const size_t MB = 1024 * 1024;
    if (ws_size < 46 * MB) return;

    char* w = (char*)d_ws;
    _Float16* Whi  = (_Float16*)(w);             // 5 MB  [0,5)
    _Float16* Wlo  = (_Float16*)(w + 5 * MB);    // 5 MB  [5,10)
    float*    qf32 = (float*)(w + 10 * MB);      // 16 MB [10,26)
    float*    kf32 = (float*)(w + 26 * MB);      // 4 MB  [26,30)
    float*    vf32 = (float*)(w + 30 * MB);      // 4 MB  [30,34)
    _Float16* qh   = (_Float16*)(w + 34 * MB);   // 8 MB  [34,42)
    _Float16* kh   = (_Float16*)(w + 42 * MB);   // 2 MB  [42,44)
    _Float16* vth  = (_Float16*)(w + 44 * MB);   // 2 MB  [44,46)
    // aliases (lifetimes disjoint):
    _Float16* hs_h  = qh;                        // dead once rope writes qh
    float2*   tab   = (float2*)vth;              // dead once vtrans writes vth
    _Float16* ctx_h = (_Float16*)qf32;           // qf32 dead after rope

    // zero-init split-K accumulation targets (graph-capturable async memsets)
    hipMemsetAsync(qf32, 0, 16 * MB, stream);
    hipMemsetAsync(kf32, 0, 4 * MB, stream);
    hipMemsetAsync(vf32, 0, 4 * MB, stream);
    hipMemsetAsync(out, 0, (size_t)out_size * sizeof(float), stream);

    tab_kernel<<<256, 256, 0, stream>>>(tab);
    prep_w_kernel<<<1280, 256, 0, stream>>>(Wq, Wk, Wv, Wo, Whi, Wlo);
    prep_a_kernel<<<2048, 256, 0, stream>>>(hs, hs_h);
    gemm2p_kernel<0><<<dim3(12, 32, 2), 256, 0, stream>>>(
        hs_h, Whi, Wlo, 0, bq, bk, bv, qf32, kf32, vf32);
    rope_half_kernel<<<(B_ * (NH + NKV) * T_ * 32) / 256, 256, 0, stream>>>(
        qf32, kf32, tab, qh, kh);
    vtrans_kernel<<<dim3(T_ / 64, B_ * NKV), 256, 0, stream>>>(vf32, vth);
    attn_kernel<<<dim3(T_ / 64, B_ * NH), 128, 0, stream>>>(qh, kh, vth, ctx_h);
    gemm2p_kernel<1><<<dim3(8, 32, 2), 256, 0, stream>>>(
        ctx_h, Whi, Wlo, 12, bo, nullptr, nullptr, out, nullptr, nullptr);
}

// Round 9
// 259.270 us; speedup vs baseline: 1.1845x; 1.1845x over previous
//
#include <hip/hip_runtime.h>
#include <math.h>

// GQA block. Round 8b: r6 structure + r7's conflict-free permuted-V b128
// frags, attention split over KEYS (ks=2, 4 blocks/CU) with fp16 O-partials
// + fp32 l-partials and a combine kernel; exp2-folded softmax scale.
// (r8 compile fix: dropped cvt_pkrtz builtin, plain casts.)
// B=2,T=2048,DIM=1024,H=16,HKV=4,HD=64.

#define B_   2
#define T_   2048
#define DIM_ 1024
#define NH   16
#define NKV  4
#define HD_  64
#define BT_  (B_ * T_)

typedef _Float16 half8_t __attribute__((ext_vector_type(8)));
typedef _Float16 half4_t __attribute__((ext_vector_type(4)));
typedef float    f32x4   __attribute__((ext_vector_type(4)));

__device__ __forceinline__ void async_copy16(_Float16* lds, const _Float16* g) {
    __builtin_amdgcn_global_load_lds(
        (const __attribute__((address_space(1))) void*)g,
        (__attribute__((address_space(3))) void*)lds, 16, 0, 0);
}

// ---------------------------------------------------------------------------
// Kernel 0: RoPE sincos table: tab[t*32+i] = (cos, sin)(t * 10000^(-i/32))
// ---------------------------------------------------------------------------
__global__ __launch_bounds__(256) void tab_kernel(float2* __restrict__ tab)
{
    int gid = blockIdx.x * 256 + threadIdx.x;   // 0..65535
    int t = gid >> 5, i = gid & 31;
    double invf = pow(10000.0, -(double)i / 32.0);
    double ang  = (double)t * invf;
    tab[gid] = make_float2((float)cos(ang), (float)sin(ang));
}

// ---------------------------------------------------------------------------
// Kernel 1: weight prep (validated r3-r7). fp32 W rows (2560: Wq|Wk|Wv|Wo) ->
// fp16 hi/lo planes, MFMA-fragment-swizzled chunks:
// c = ((nb*32+kb)*4 + k8)*128 + nl  holds  W[nb*128+nl][kb*32+k8*8 .. +8]
// ---------------------------------------------------------------------------
__global__ __launch_bounds__(256) void prep_w_kernel(
    const float* __restrict__ Wq, const float* __restrict__ Wk,
    const float* __restrict__ Wv, const float* __restrict__ Wo,
    _Float16* __restrict__ Whi, _Float16* __restrict__ Wlo)
{
    int c = blockIdx.x * 256 + threadIdx.x;       // 0..327679
    int nl = c & 127, k8 = (c >> 7) & 3, kb = (c >> 9) & 31, nb = c >> 14;
    int n = nb * 128 + nl, k = kb * 32 + k8 * 8;
    const float* src;
    if (n < 1024)      src = Wq + (size_t)n * 1024;
    else if (n < 1280) src = Wk + (size_t)(n - 1024) * 1024;
    else if (n < 1536) src = Wv + (size_t)(n - 1280) * 1024;
    else               src = Wo + (size_t)(n - 1536) * 1024;
    float4 f0 = *(const float4*)(src + k);
    float4 f1 = *(const float4*)(src + k + 4);
    float xs[8] = {f0.x, f0.y, f0.z, f0.w, f1.x, f1.y, f1.z, f1.w};
    half8_t hi, lo;
#pragma unroll
    for (int j = 0; j < 8; ++j) {
        _Float16 h = (_Float16)xs[j];
        hi[j] = h;
        lo[j] = (_Float16)(xs[j] - (float)h);
    }
    *(half8_t*)&Whi[(size_t)c * 8] = hi;
    *(half8_t*)&Wlo[(size_t)c * 8] = lo;
}

// ---------------------------------------------------------------------------
// Kernel 2: A prep: hs fp32 [4096 x 1024] -> fp16 swizzled chunks
// [mb][kb][k8][ml]*8.
// ---------------------------------------------------------------------------
__global__ __launch_bounds__(256) void prep_a_kernel(
    const float* __restrict__ hs, _Float16* __restrict__ Ah)
{
    int gid = blockIdx.x * 256 + threadIdx.x;    // 0..524287
    int k8 = gid & 3, kb = (gid >> 2) & 31, ml = (gid >> 7) & 127, mb = gid >> 14;
    const float* src = hs + (size_t)(mb * 128 + ml) * 1024 + kb * 32 + k8 * 8;
    float4 f0 = *(const float4*)src;
    float4 f1 = *(const float4*)(src + 4);
    half8_t hv;
    hv[0] = (_Float16)f0.x; hv[1] = (_Float16)f0.y;
    hv[2] = (_Float16)f0.z; hv[3] = (_Float16)f0.w;
    hv[4] = (_Float16)f1.x; hv[5] = (_Float16)f1.y;
    hv[6] = (_Float16)f1.z; hv[7] = (_Float16)f1.w;
    size_t c = ((size_t)(mb * 32 + kb) * 4 + k8) * 128 + ml;
    *(half8_t*)&Ah[c * 8] = hv;
}

// ---------------------------------------------------------------------------
// Kernel 3: 2-pass MFMA GEMM, all-DMA staging (r6, validated). C = A@(Whi+Wlo)^T
// + bias. 128x128 tile, BK=32, dbuf. MODE 0: QKV scatter. MODE 1: row-major.
// ---------------------------------------------------------------------------
template <int MODE>
__global__ __launch_bounds__(256, 3) void gemm2p_kernel(
    const _Float16* __restrict__ Ah,
    const _Float16* __restrict__ Whi, const _Float16* __restrict__ Wlo,
    int nb0,
    const float* __restrict__ bq, const float* __restrict__ bk,
    const float* __restrict__ bv,
    float* __restrict__ o0, float* __restrict__ o1, float* __restrict__ o2)
{
    __shared__ _Float16 sA [2][4096];
    __shared__ _Float16 sBh[2][4096];
    __shared__ _Float16 sBl[2][4096];

    const int tid  = threadIdx.x;
    const int w    = tid >> 6, lane = tid & 63;
    const int quad = lane >> 4, l15 = lane & 15;
    const int wm = w >> 1, wn = w & 1;
    const int mb   = blockIdx.y;
    const int nblk = blockIdx.x;

    const _Float16* AB   = Ah  + (size_t)mb * 32 * 4096;
    const _Float16* WhiB = Whi + (size_t)(nb0 + nblk) * 32 * 4096;
    const _Float16* WloB = Wlo + (size_t)(nb0 + nblk) * 32 * 4096;

    f32x4 acc[4][4];
#pragma unroll
    for (int mt = 0; mt < 4; ++mt)
#pragma unroll
        for (int nt = 0; nt < 4; ++nt) {
            f32x4 z = {0.f, 0.f, 0.f, 0.f};
            acc[mt][nt] = z;
        }

#define GEMM_STAGE(buf, kbl)                                                  \
    {                                                                         \
        const _Float16* ga = AB   + (size_t)(kbl) * 4096;                     \
        const _Float16* gh = WhiB + (size_t)(kbl) * 4096;                     \
        const _Float16* gl = WloB + (size_t)(kbl) * 4096;                     \
        _Pragma("unroll")                                                     \
        for (int p = 0; p < 2; ++p) {                                         \
            int cb = p * 256 + w * 64;                                        \
            async_copy16(&sA [buf][cb * 8], ga + (size_t)(cb + lane) * 8);    \
            async_copy16(&sBh[buf][cb * 8], gh + (size_t)(cb + lane) * 8);    \
            async_copy16(&sBl[buf][cb * 8], gl + (size_t)(cb + lane) * 8);    \
        }                                                                     \
    }

    GEMM_STAGE(0, 0);
    __syncthreads();

    for (int kb = 0; kb < 32; ++kb) {
        const int cur = kb & 1;
        if (kb + 1 < 32) { GEMM_STAGE(cur ^ 1, kb + 1); }

        half8_t af[4], bf[4], blv[4];
#pragma unroll
        for (int mt = 0; mt < 4; ++mt) {
            int ch = quad * 128 + wm * 64 + mt * 16 + l15;
            af[mt] = *(const half8_t*)&sA[cur][ch * 8];
        }
#pragma unroll
        for (int nt = 0; nt < 4; ++nt) {
            int ch = quad * 128 + wn * 64 + nt * 16 + l15;
            bf[nt]  = *(const half8_t*)&sBh[cur][ch * 8];
            blv[nt] = *(const half8_t*)&sBl[cur][ch * 8];
        }
#pragma unroll
        for (int mt = 0; mt < 4; ++mt)
#pragma unroll
            for (int nt = 0; nt < 4; ++nt) {
                acc[mt][nt] = __builtin_amdgcn_mfma_f32_16x16x32_f16(af[mt], bf[nt],  acc[mt][nt], 0, 0, 0);
                acc[mt][nt] = __builtin_amdgcn_mfma_f32_16x16x32_f16(af[mt], blv[nt], acc[mt][nt], 0, 0, 0);
            }
        __syncthreads();
    }

    const int m0 = mb * 128;
    if constexpr (MODE == 0) {
        int nreg = nblk * 128;
        const float* bias; float* outp; int nh2, nbl;
        if (nreg < 1024)      { bias = bq; outp = o0; nh2 = NH;  nbl = nreg; }
        else if (nreg < 1280) { bias = bk; outp = o1; nh2 = NKV; nbl = nreg - 1024; }
        else                  { bias = bv; outp = o2; nh2 = NKV; nbl = nreg - 1280; }
        int hh = (nbl + wn * 64) >> 6;
#pragma unroll
        for (int mt = 0; mt < 4; ++mt)
#pragma unroll
            for (int r = 0; r < 4; ++r) {
                int m  = m0 + wm * 64 + mt * 16 + quad * 4 + r;
                int b_ = m >> 11, t_ = m & 2047;
                float* cp = outp + (((size_t)(b_ * nh2 + hh)) * T_ + t_) * 64;
#pragma unroll
                for (int nt = 0; nt < 4; ++nt) {
                    int dd = nt * 16 + l15;
                    cp[dd] = acc[mt][nt][r] + bias[hh * 64 + dd];
                }
            }
    } else {
        int n0 = nblk * 128 + wn * 64;
#pragma unroll
        for (int mt = 0; mt < 4; ++mt)
#pragma unroll
            for (int r = 0; r < 4; ++r) {
                int m = m0 + wm * 64 + mt * 16 + quad * 4 + r;
#pragma unroll
                for (int nt = 0; nt < 4; ++nt) {
                    int n = n0 + nt * 16 + l15;
                    o0[(size_t)m * 1024 + n] = acc[mt][nt][r] + bq[n];
                }
            }
    }
#undef GEMM_STAGE
}

// ---------------------------------------------------------------------------
// Kernel 4: RoPE via table, fp32 -> fp16. q scaled by 0.125*log2(e) so the
// softmax can use exp2 directly (exp(s) = 2^(s*log2e)).
// ---------------------------------------------------------------------------
__global__ __launch_bounds__(256) void rope_half_kernel(
    const float* __restrict__ qf, const float* __restrict__ kf,
    const float2* __restrict__ tab,
    _Float16* __restrict__ qh, _Float16* __restrict__ kh)
{
    int gid = blockIdx.x * 256 + threadIdx.x;
    int i   = gid & 31;
    int row = gid >> 5;
    const float* src; _Float16* dst; int t; float sc;
    if (row < B_ * NH * T_) {
        src = qf + (size_t)row * 64; dst = qh + (size_t)row * 64;
        t = row & (T_ - 1); sc = 0.125f * 1.44269504088896f;
    } else {
        int r = row - B_ * NH * T_;
        src = kf + (size_t)r * 64; dst = kh + (size_t)r * 64;
        t = r & (T_ - 1); sc = 1.0f;
    }
    float2 cs = tab[t * 32 + i];
    float c = cs.x, s = cs.y;
    float x0 = src[i], x1 = src[i + 32];
    float xe = src[2 * i], xo = src[2 * i + 1];
    dst[i]      = (_Float16)((x0 * c - xo * s) * sc);
    dst[i + 32] = (_Float16)((x1 * c + xe * s) * sc);
}

// ---------------------------------------------------------------------------
// Kernel 5: V transpose fp32 [b,hkv,t,d] -> fp16 [b,hkv,d,t'] with keys
// PERMUTED within each 64-key group (r7, validated, 0 bank conflicts):
// original k = 16t+4q+j stored at p = q*16 + t*4 + j.
// ---------------------------------------------------------------------------
__global__ __launch_bounds__(256) void vtrans_kernel(
    const float* __restrict__ vf, _Float16* __restrict__ vth)
{
    __shared__ float ts[64][65];
    const int bhk = blockIdx.y;
    const int t0  = blockIdx.x * 64;
    const int tid = threadIdx.x;
    const float* src = vf + (size_t)bhk * T_ * 64 + (size_t)t0 * 64;

    int row = tid >> 2, c0 = (tid & 3) * 16;
#pragma unroll
    for (int j = 0; j < 16; ++j)
        ts[row][c0 + j] = src[(size_t)row * 64 + c0 + j];
    __syncthreads();

    int drow = tid >> 2;                  // d index 0..63
    int t4   = (c0 >> 4) * 4;             // t = c0/16
    _Float16* dstb = vth + (size_t)bhk * 64 * T_ + (size_t)drow * T_ + t0;
#pragma unroll
    for (int q = 0; q < 4; ++q) {
        half4_t hv;
#pragma unroll
        for (int j = 0; j < 4; ++j)
            hv[j] = (_Float16)ts[c0 + q * 4 + j][drow];
        *(half4_t*)&dstb[q * 16 + t4] = hv;
    }
}

// ---------------------------------------------------------------------------
// Kernel 6: flash attention, KEY-SPLIT ks=2. 128q/block, 256 threads, 4 waves
// x 32q (r6 amortization). S^T = K Q^T -> exp2 -> P register-direct into
// 16x16x16 PV MFMAs with permuted-V b128 A-frags (r7). Emits unnormalized
// fp16 O-partials (O^T per q,d) + fp32 l-partials; combine_kernel finishes.
// K LDS chunk g*64 + t*16 + l  <-> K[key=16t+l][d=8g..+8]
// V LDS chunk g*64 + dt*16 + l <-> V^T[d=16dt+l][perm-pos 8g..+8]
// ---------------------------------------------------------------------------
__global__ __launch_bounds__(256, 3) void attn_kernel(
    const _Float16* __restrict__ qh, const _Float16* __restrict__ kh,
    const _Float16* __restrict__ vth,
    _Float16* __restrict__ Oh,     // [ks][bh][qt][128 rows][64 d] fp16
    float* __restrict__ lbuf)      // [ks][bh*2048 rows] fp32
{
    __shared__ _Float16 Ks[2][4096];
    __shared__ _Float16 Vs[2][4096];

    const int qt = blockIdx.x;          // 0..15 (128-q tiles)
    const int bh = blockIdx.y;          // 0..31
    const int ks = blockIdx.z;          // 0..1 key split
    const int b  = bh >> 4, h = bh & 15, hk = h >> 2;
    const int tid  = threadIdx.x;
    const int w    = tid >> 6;
    const int lane = tid & 63;
    const int quad = lane >> 4, l15 = lane & 15;

    // Q B-frags for 2 strips of 16 q-rows (scale 0.125*log2e folded at rope)
    half8_t aq0[2], aq1[2];
#pragma unroll
    for (int s = 0; s < 2; ++s) {
        const _Float16* Qb = qh +
            ((size_t)(b * NH + h) * T_ + qt * 128 + w * 32 + s * 16 + l15) * 64 + quad * 8;
        aq0[s] = *(const half8_t*)(Qb);
        aq1[s] = *(const half8_t*)(Qb + 32);
    }

    const _Float16* Kb = kh  + (size_t)(b * NKV + hk) * (T_ * 64);
    const _Float16* Vb = vth + (size_t)(b * NKV + hk) * (64 * T_);

#define ATTN_STAGE(buf, ktile)                                                \
    {                                                                         \
        _Float16* kd = &Ks[buf][0];                                           \
        _Float16* vd = &Vs[buf][0];                                           \
        _Pragma("unroll")                                                     \
        for (int p = 0; p < 2; ++p) {                                         \
            int cb = p * 256 + w * 64;                                        \
            int c  = cb + lane;                                               \
            int l_ = c & 15, t_ = (c >> 4) & 3, g_ = c >> 6;                  \
            const _Float16* kg = Kb + ((size_t)((ktile) * 64 + t_ * 16 + l_)) * 64 + g_ * 8; \
            const _Float16* vg = Vb + ((size_t)(t_ * 16 + l_)) * T_ + (ktile) * 64 + g_ * 8; \
            async_copy16(kd + cb * 8, kg);                                    \
            async_copy16(vd + cb * 8, vg);                                    \
        }                                                                     \
    }

    float l_i[2] = {0.0f, 0.0f};
    f32x4 o_acc[2][4];
#pragma unroll
    for (int s = 0; s < 2; ++s)
#pragma unroll
        for (int dt = 0; dt < 4; ++dt) { f32x4 z = {0.f,0.f,0.f,0.f}; o_acc[s][dt] = z; }

    const int kt0 = ks * 16;            // 16 k-tiles per split
    ATTN_STAGE(0, kt0);
    __syncthreads();

    for (int kt = 0; kt < 16; ++kt) {
        const int cur = kt & 1;
        if (kt + 1 < 16) { ATTN_STAGE(cur ^ 1, kt0 + kt + 1); }

        // K A-frags: chunk quad*64 + t*16 + l15 (d=8quad), +256 chunks d+32
        half8_t ak0[4], ak1[4];
#pragma unroll
        for (int t = 0; t < 4; ++t) {
            const _Float16* kr = &Ks[cur][(quad * 64 + t * 16 + l15) * 8];
            ak0[t] = *(const half8_t*)(kr);
            ak1[t] = *(const half8_t*)(kr + 2048);
        }
        // V A-frags: b128 per (t-pair u, dt): chunk (2*quad+u)*64 + dt*16 + l15
        half8_t av8[2][4];
#pragma unroll
        for (int u = 0; u < 2; ++u)
#pragma unroll
            for (int dt = 0; dt < 4; ++dt)
                av8[u][dt] = *(const half8_t*)&Vs[cur][((2 * quad + u) * 64 + dt * 16 + l15) * 8];

#pragma unroll
        for (int s = 0; s < 2; ++s) {
            f32x4 sv[4];
#pragma unroll
            for (int t = 0; t < 4; ++t) {
                f32x4 z = {0.f,0.f,0.f,0.f};
                z     = __builtin_amdgcn_mfma_f32_16x16x32_f16(ak0[t], aq0[s], z, 0, 0, 0);
                sv[t] = __builtin_amdgcn_mfma_f32_16x16x32_f16(ak1[t], aq1[s], z, 0, 0, 0);
            }
#pragma unroll
            for (int t = 0; t < 4; ++t) {
                float p0 = exp2f(sv[t][0]);
                float p1 = exp2f(sv[t][1]);
                float p2 = exp2f(sv[t][2]);
                float p3 = exp2f(sv[t][3]);
                l_i[s] += (p0 + p1) + (p2 + p3);
                half4_t pb;
                pb[0] = (_Float16)p0; pb[1] = (_Float16)p1;
                pb[2] = (_Float16)p2; pb[3] = (_Float16)p3;
                int u = t >> 1, hf = (t & 1) * 4;
#pragma unroll
                for (int dt = 0; dt < 4; ++dt) {
                    half4_t a4;
                    a4[0] = av8[u][dt][hf + 0];
                    a4[1] = av8[u][dt][hf + 1];
                    a4[2] = av8[u][dt][hf + 2];
                    a4[3] = av8[u][dt][hf + 3];
                    o_acc[s][dt] = __builtin_amdgcn_mfma_f32_16x16x16f16(
                        a4, pb, o_acc[s][dt], 0, 0, 0);
                }
            }
        }
        __syncthreads();
    }

    // epilogue: reduce l across quads; write unnormalized fp16 O^T partials.
    _Float16* Ohb = Oh + (size_t)ks * (32u * 16 * 128 * 64);
#pragma unroll
    for (int s = 0; s < 2; ++s) {
        float l = l_i[s];
        l += __shfl_xor(l, 16);
        l += __shfl_xor(l, 32);
        int rowin = w * 32 + s * 16 + l15;
        if (quad == 0)
            lbuf[(size_t)ks * (32 * 2048) + bh * 2048 + qt * 128 + rowin] = l;
        _Float16* op = Ohb + (((size_t)(bh * 16 + qt) * 128) + rowin) * 64;
#pragma unroll
        for (int dt = 0; dt < 4; ++dt) {
            int d = 16 * dt + 4 * quad;
            half4_t hv;
            hv[0] = (_Float16)o_acc[s][dt][0];
            hv[1] = (_Float16)o_acc[s][dt][1];
            hv[2] = (_Float16)o_acc[s][dt][2];
            hv[3] = (_Float16)o_acc[s][dt][3];
            *(half4_t*)&op[d] = hv;
        }
    }
#undef ATTN_STAGE
}

// ---------------------------------------------------------------------------
// Kernel 7: combine key-splits: ctx = (O0+O1)/(l0+l1), written as swizzled
// fp16 chunks for the out-GEMM.
// ---------------------------------------------------------------------------
__global__ __launch_bounds__(256) void combine_kernel(
    const _Float16* __restrict__ Oh, const float* __restrict__ lbuf,
    _Float16* __restrict__ ctx_h)
{
    int gid = blockIdx.x * 256 + threadIdx.x;    // 0..524287
    int d8 = gid & 7, t = (gid >> 3) & 2047, bh = gid >> 14;
    int b = bh >> 4, h = bh & 15;

    size_t oidx = ((((size_t)(bh * 16 + (t >> 7)) * 128) + (t & 127)) * 64 + d8 * 8);
    const size_t SPLIT = 32u * 16 * 128 * 64;
    half8_t o0 = *(const half8_t*)&Oh[oidx];
    half8_t o1 = *(const half8_t*)&Oh[SPLIT + oidx];
    float l = lbuf[bh * 2048 + t] + lbuf[32 * 2048 + bh * 2048 + t];
    float inv = 1.0f / l;

    half8_t r;
#pragma unroll
    for (int j = 0; j < 8; ++j)
        r[j] = (_Float16)(((float)o0[j] + (float)o1[j]) * inv);

    int m = b * 2048 + t, mb = m >> 7, ml = m & 127;
    int kb = 2 * h + (d8 >> 2), k8 = d8 & 3;
    *(half8_t*)&ctx_h[(((size_t)(mb * 32 + kb) * 4 + k8) * 128 + ml) * 8] = r;
}

// ---------------------------------------------------------------------------
extern "C" void kernel_launch(void* const* d_in, const int* in_sizes, int n_in,
                              void* d_out, int out_size, void* d_ws, size_t ws_size,
                              hipStream_t stream)
{
    const float* hs = (const float*)d_in[0];
    const float* Wq = (const float*)d_in[1];
    const float* bq = (const float*)d_in[2];
    const float* Wk = (const float*)d_in[3];
    const float* bk = (const float*)d_in[4];
    const float* Wv = (const float*)d_in[5];
    const float* bv = (const float*)d_in[6];
    const float* Wo = (const float*)d_in[7];
    const float* bo = (const float*)d_in[8];
    float* out = (float*)d_out;

    const size_t MB = 1024 * 1024;
    if (ws_size < 46 * MB) return;

    char* w = (char*)d_ws;
    _Float16* Whi  = (_Float16*)(w);             // 5 MB  [0,5)
    _Float16* Wlo  = (_Float16*)(w + 5 * MB);    // 5 MB  [5,10)
    float*    qf32 = (float*)(w + 10 * MB);      // 16 MB [10,26)
    float*    kf32 = (float*)(w + 26 * MB);      // 4 MB  [26,30)
    float*    vf32 = (float*)(w + 30 * MB);      // 4 MB  [30,34)
    _Float16* qh   = (_Float16*)(w + 34 * MB);   // 8 MB  [34,42)
    _Float16* kh   = (_Float16*)(w + 42 * MB);   // 2 MB  [42,44)
    _Float16* vth  = (_Float16*)(w + 44 * MB);   // 2 MB  [44,46)
    // aliases (lifetimes disjoint):
    _Float16* hs_h  = qh;                        // dead once rope writes qh
    float2*   tab   = (float2*)vth;              // dead once vtrans writes vth
    _Float16* ctx_h = (_Float16*)(w + 10 * MB);  // [10,18): qf32 dead after rope
    _Float16* Ohbuf = (_Float16*)(w + 18 * MB);  // [18,34): 2 x 8 MB partials
    float*    lbuf  = out;                       // 512 KB scratch; out rewritten

    tab_kernel<<<256, 256, 0, stream>>>(tab);
    prep_w_kernel<<<1280, 256, 0, stream>>>(Wq, Wk, Wv, Wo, Whi, Wlo);
    prep_a_kernel<<<2048, 256, 0, stream>>>(hs, hs_h);
    gemm2p_kernel<0><<<dim3(12, 32), 256, 0, stream>>>(
        hs_h, Whi, Wlo, 0, bq, bk, bv, qf32, kf32, vf32);
    rope_half_kernel<<<(B_ * (NH + NKV) * T_ * 32) / 256, 256, 0, stream>>>(
        qf32, kf32, tab, qh, kh);
    vtrans_kernel<<<dim3(T_ / 64, B_ * NKV), 256, 0, stream>>>(vf32, vth);
    attn_kernel<<<dim3(16, 32, 2), 256, 0, stream>>>(qh, kh, vth, Ohbuf, lbuf);
    combine_kernel<<<2048, 256, 0, stream>>>(Ohbuf, lbuf, ctx_h);
    gemm2p_kernel<1><<<dim3(8, 32), 256, 0, stream>>>(
        ctx_h, Whi, Wlo, 12, bo, nullptr, nullptr, out, nullptr, nullptr);
}

// Round 10
// 254.775 us; speedup vs baseline: 1.2054x; 1.0176x over previous
//
#include <hip/hip_runtime.h>
#include <math.h>

// GQA block. Round 10: attention reverted to r6 shape (128q/block, 4 waves,
// full k-loop, direct swizzled-ctx write) keeping permuted-V b128 frags (r7)
// + exp2 scale (r8). GEMMs re-tiled 128x64 / 128-thread blocks for 2-3
// blocks/CU (QKV grid 768, out 512). B=2,T=2048,DIM=1024,H=16,HKV=4,HD=64.

#define B_   2
#define T_   2048
#define DIM_ 1024
#define NH   16
#define NKV  4
#define HD_  64
#define BT_  (B_ * T_)

typedef _Float16 half8_t __attribute__((ext_vector_type(8)));
typedef _Float16 half4_t __attribute__((ext_vector_type(4)));
typedef float    f32x4   __attribute__((ext_vector_type(4)));

__device__ __forceinline__ void async_copy16(_Float16* lds, const _Float16* g) {
    __builtin_amdgcn_global_load_lds(
        (const __attribute__((address_space(1))) void*)g,
        (__attribute__((address_space(3))) void*)lds, 16, 0, 0);
}

// ---------------------------------------------------------------------------
// Kernel 0: RoPE sincos table: tab[t*32+i] = (cos, sin)(t * 10000^(-i/32))
// ---------------------------------------------------------------------------
__global__ __launch_bounds__(256) void tab_kernel(float2* __restrict__ tab)
{
    int gid = blockIdx.x * 256 + threadIdx.x;   // 0..65535
    int t = gid >> 5, i = gid & 31;
    double invf = pow(10000.0, -(double)i / 32.0);
    double ang  = (double)t * invf;
    tab[gid] = make_float2((float)cos(ang), (float)sin(ang));
}

// ---------------------------------------------------------------------------
// Kernel 1: weight prep (validated r3-r9). fp32 W rows (2560: Wq|Wk|Wv|Wo) ->
// fp16 hi/lo planes, MFMA-fragment-swizzled chunks:
// c = ((nb*32+kb)*4 + k8)*128 + nl  holds  W[nb*128+nl][kb*32+k8*8 .. +8]
// ---------------------------------------------------------------------------
__global__ __launch_bounds__(256) void prep_w_kernel(
    const float* __restrict__ Wq, const float* __restrict__ Wk,
    const float* __restrict__ Wv, const float* __restrict__ Wo,
    _Float16* __restrict__ Whi, _Float16* __restrict__ Wlo)
{
    int c = blockIdx.x * 256 + threadIdx.x;       // 0..327679
    int nl = c & 127, k8 = (c >> 7) & 3, kb = (c >> 9) & 31, nb = c >> 14;
    int n = nb * 128 + nl, k = kb * 32 + k8 * 8;
    const float* src;
    if (n < 1024)      src = Wq + (size_t)n * 1024;
    else if (n < 1280) src = Wk + (size_t)(n - 1024) * 1024;
    else if (n < 1536) src = Wv + (size_t)(n - 1280) * 1024;
    else               src = Wo + (size_t)(n - 1536) * 1024;
    float4 f0 = *(const float4*)(src + k);
    float4 f1 = *(const float4*)(src + k + 4);
    float xs[8] = {f0.x, f0.y, f0.z, f0.w, f1.x, f1.y, f1.z, f1.w};
    half8_t hi, lo;
#pragma unroll
    for (int j = 0; j < 8; ++j) {
        _Float16 h = (_Float16)xs[j];
        hi[j] = h;
        lo[j] = (_Float16)(xs[j] - (float)h);
    }
    *(half8_t*)&Whi[(size_t)c * 8] = hi;
    *(half8_t*)&Wlo[(size_t)c * 8] = lo;
}

// ---------------------------------------------------------------------------
// Kernel 2: A prep: hs fp32 [4096 x 1024] -> fp16 swizzled chunks
// [mb][kb][k8][ml]*8.
// ---------------------------------------------------------------------------
__global__ __launch_bounds__(256) void prep_a_kernel(
    const float* __restrict__ hs, _Float16* __restrict__ Ah)
{
    int gid = blockIdx.x * 256 + threadIdx.x;    // 0..524287
    int k8 = gid & 3, kb = (gid >> 2) & 31, ml = (gid >> 7) & 127, mb = gid >> 14;
    const float* src = hs + (size_t)(mb * 128 + ml) * 1024 + kb * 32 + k8 * 8;
    float4 f0 = *(const float4*)src;
    float4 f1 = *(const float4*)(src + 4);
    half8_t hv;
    hv[0] = (_Float16)f0.x; hv[1] = (_Float16)f0.y;
    hv[2] = (_Float16)f0.z; hv[3] = (_Float16)f0.w;
    hv[4] = (_Float16)f1.x; hv[5] = (_Float16)f1.y;
    hv[6] = (_Float16)f1.z; hv[7] = (_Float16)f1.w;
    size_t c = ((size_t)(mb * 32 + kb) * 4 + k8) * 128 + ml;
    *(half8_t*)&Ah[c * 8] = hv;
}

// ---------------------------------------------------------------------------
// Kernel 3: 2-pass MFMA GEMM, tile 128x64, BK=32, 128 threads = 2 waves
// (each wave 64 rows x 64 cols), all-DMA dbuf staging.
// W half-tile: nb = nblk>>1, column offset hb64 = (nblk&1)*64.
// MODE 0: QKV epilogue (each N-tile = exactly one head). MODE 1: row-major.
// ---------------------------------------------------------------------------
template <int MODE>
__global__ __launch_bounds__(128, 2) void gemm2p_kernel(
    const _Float16* __restrict__ Ah,
    const _Float16* __restrict__ Whi, const _Float16* __restrict__ Wlo,
    int nb0,
    const float* __restrict__ bq, const float* __restrict__ bk,
    const float* __restrict__ bv,
    float* __restrict__ o0, float* __restrict__ o1, float* __restrict__ o2)
{
    __shared__ _Float16 sA [2][4096];   // A chunks c = k8*128 + ml  (8 KB/buf)
    __shared__ _Float16 sBh[2][2048];   // B chunks c = k8*64 + nl   (4 KB/buf)
    __shared__ _Float16 sBl[2][2048];

    const int tid  = threadIdx.x;       // 0..127
    const int w    = tid >> 6, lane = tid & 63;
    const int quad = lane >> 4, l15 = lane & 15;
    const int mb   = blockIdx.y;
    const int nblk = blockIdx.x;
    const int hb64 = (nblk & 1) * 64;

    const _Float16* AB   = Ah  + (size_t)mb * 32 * 4096;
    const _Float16* WhiB = Whi + (size_t)(nb0 + (nblk >> 1)) * 32 * 4096;
    const _Float16* WloB = Wlo + (size_t)(nb0 + (nblk >> 1)) * 32 * 4096;

    f32x4 acc[4][4];
#pragma unroll
    for (int mt = 0; mt < 4; ++mt)
#pragma unroll
        for (int nt = 0; nt < 4; ++nt) {
            f32x4 z = {0.f, 0.f, 0.f, 0.f};
            acc[mt][nt] = z;
        }

    // A: 512 chunks contiguous. B half-tile: local chunk c = k8*64+nl' ->
    // global chunk g = (c>>6)*128 + hb64 + (c&63); each wave-copy of 64
    // consecutive local chunks is 1 KB contiguous in global.
#define GEMM_STAGE(buf, kbl)                                                  \
    {                                                                         \
        const _Float16* ga = AB   + (size_t)(kbl) * 4096;                     \
        const _Float16* gh = WhiB + (size_t)(kbl) * 4096;                     \
        const _Float16* gl = WloB + (size_t)(kbl) * 4096;                     \
        _Pragma("unroll")                                                     \
        for (int p = 0; p < 4; ++p) {                                         \
            int cb = p * 128 + w * 64;                                        \
            async_copy16(&sA[buf][cb * 8], ga + (size_t)(cb + lane) * 8);     \
        }                                                                     \
        _Pragma("unroll")                                                     \
        for (int p = 0; p < 2; ++p) {                                         \
            int cb = p * 128 + w * 64;                                        \
            int g  = (cb >> 6) * 128 + hb64 + lane;                           \
            async_copy16(&sBh[buf][cb * 8], gh + (size_t)g * 8);              \
            async_copy16(&sBl[buf][cb * 8], gl + (size_t)g * 8);              \
        }                                                                     \
    }

    GEMM_STAGE(0, 0);
    __syncthreads();

    for (int kb = 0; kb < 32; ++kb) {
        const int cur = kb & 1;
        if (kb + 1 < 32) { GEMM_STAGE(cur ^ 1, kb + 1); }

        half8_t af[4], bf[4], blv[4];
#pragma unroll
        for (int mt = 0; mt < 4; ++mt) {
            int ch = quad * 128 + w * 64 + mt * 16 + l15;
            af[mt] = *(const half8_t*)&sA[cur][ch * 8];
        }
#pragma unroll
        for (int nt = 0; nt < 4; ++nt) {
            int ch = quad * 64 + nt * 16 + l15;
            bf[nt]  = *(const half8_t*)&sBh[cur][ch * 8];
            blv[nt] = *(const half8_t*)&sBl[cur][ch * 8];
        }
#pragma unroll
        for (int mt = 0; mt < 4; ++mt)
#pragma unroll
            for (int nt = 0; nt < 4; ++nt) {
                acc[mt][nt] = __builtin_amdgcn_mfma_f32_16x16x32_f16(af[mt], bf[nt],  acc[mt][nt], 0, 0, 0);
                acc[mt][nt] = __builtin_amdgcn_mfma_f32_16x16x32_f16(af[mt], blv[nt], acc[mt][nt], 0, 0, 0);
            }
        __syncthreads();
    }

    const int m0 = mb * 128 + w * 64;
    if constexpr (MODE == 0) {
        const float* bias; float* outp; int nh2, hh;
        if (nblk < 16)      { bias = bq; outp = o0; nh2 = NH;  hh = nblk; }
        else if (nblk < 20) { bias = bk; outp = o1; nh2 = NKV; hh = nblk - 16; }
        else                { bias = bv; outp = o2; nh2 = NKV; hh = nblk - 20; }
#pragma unroll
        for (int mt = 0; mt < 4; ++mt)
#pragma unroll
            for (int r = 0; r < 4; ++r) {
                int m  = m0 + mt * 16 + quad * 4 + r;
                int b_ = m >> 11, t_ = m & 2047;
                float* cp = outp + (((size_t)(b_ * nh2 + hh)) * T_ + t_) * 64;
#pragma unroll
                for (int nt = 0; nt < 4; ++nt) {
                    int dd = nt * 16 + l15;
                    cp[dd] = acc[mt][nt][r] + bias[hh * 64 + dd];
                }
            }
    } else {
        int n0 = nblk * 64;
#pragma unroll
        for (int mt = 0; mt < 4; ++mt)
#pragma unroll
            for (int r = 0; r < 4; ++r) {
                int m = m0 + mt * 16 + quad * 4 + r;
#pragma unroll
                for (int nt = 0; nt < 4; ++nt) {
                    int n = n0 + nt * 16 + l15;
                    o0[(size_t)m * 1024 + n] = acc[mt][nt][r] + bq[n];
                }
            }
    }
#undef GEMM_STAGE
}

// ---------------------------------------------------------------------------
// Kernel 4: RoPE via table, fp32 -> fp16. q scaled by 0.125*log2(e) so the
// softmax can use exp2 directly.
// ---------------------------------------------------------------------------
__global__ __launch_bounds__(256) void rope_half_kernel(
    const float* __restrict__ qf, const float* __restrict__ kf,
    const float2* __restrict__ tab,
    _Float16* __restrict__ qh, _Float16* __restrict__ kh)
{
    int gid = blockIdx.x * 256 + threadIdx.x;
    int i   = gid & 31;
    int row = gid >> 5;
    const float* src; _Float16* dst; int t; float sc;
    if (row < B_ * NH * T_) {
        src = qf + (size_t)row * 64; dst = qh + (size_t)row * 64;
        t = row & (T_ - 1); sc = 0.125f * 1.44269504088896f;
    } else {
        int r = row - B_ * NH * T_;
        src = kf + (size_t)r * 64; dst = kh + (size_t)r * 64;
        t = r & (T_ - 1); sc = 1.0f;
    }
    float2 cs = tab[t * 32 + i];
    float c = cs.x, s = cs.y;
    float x0 = src[i], x1 = src[i + 32];
    float xe = src[2 * i], xo = src[2 * i + 1];
    dst[i]      = (_Float16)((x0 * c - xo * s) * sc);
    dst[i + 32] = (_Float16)((x1 * c + xe * s) * sc);
}

// ---------------------------------------------------------------------------
// Kernel 5: V transpose fp32 [b,hkv,t,d] -> fp16 [b,hkv,d,t'] with keys
// PERMUTED within each 64-key group (r7/r9, validated, 0 bank conflicts):
// original k = 16t+4q+j stored at p = q*16 + t*4 + j.
// ---------------------------------------------------------------------------
__global__ __launch_bounds__(256) void vtrans_kernel(
    const float* __restrict__ vf, _Float16* __restrict__ vth)
{
    __shared__ float ts[64][65];
    const int bhk = blockIdx.y;
    const int t0  = blockIdx.x * 64;
    const int tid = threadIdx.x;
    const float* src = vf + (size_t)bhk * T_ * 64 + (size_t)t0 * 64;

    int row = tid >> 2, c0 = (tid & 3) * 16;
#pragma unroll
    for (int j = 0; j < 16; ++j)
        ts[row][c0 + j] = src[(size_t)row * 64 + c0 + j];
    __syncthreads();

    int drow = tid >> 2;                  // d index 0..63
    int t4   = (c0 >> 4) * 4;             // t = c0/16
    _Float16* dstb = vth + (size_t)bhk * 64 * T_ + (size_t)drow * T_ + t0;
#pragma unroll
    for (int q = 0; q < 4; ++q) {
        half4_t hv;
#pragma unroll
        for (int j = 0; j < 4; ++j)
            hv[j] = (_Float16)ts[c0 + q * 4 + j][drow];
        *(half4_t*)&dstb[q * 16 + t4] = hv;
    }
}

// ---------------------------------------------------------------------------
// Kernel 6: flash attention (r6 shape, validated pieces). 128q/block, 256
// threads, 4 waves x 32q, full 32-iter k-loop. S^T = K Q^T -> exp2 -> P
// register-direct into 16x16x16 PV MFMAs with permuted-V b128 A-frags.
// Fixed-max softmax. Direct normalized write to swizzled fp16 ctx chunks.
// K LDS chunk g*64 + t*16 + l  <-> K[key=16t+l][d=8g..+8]
// V LDS chunk g*64 + dt*16 + l <-> V^T[d=16dt+l][perm-pos 8g..+8]
// ---------------------------------------------------------------------------
__global__ __launch_bounds__(256, 2) void attn_kernel(
    const _Float16* __restrict__ qh, const _Float16* __restrict__ kh,
    const _Float16* __restrict__ vth, _Float16* __restrict__ ctx_h)
{
    __shared__ _Float16 Ks[2][4096];
    __shared__ _Float16 Vs[2][4096];

    const int qt = blockIdx.x;          // 0..15 (128-q tiles)
    const int bh = blockIdx.y;          // 0..31
    const int b  = bh >> 4, h = bh & 15, hk = h >> 2;
    const int tid  = threadIdx.x;
    const int w    = tid >> 6;
    const int lane = tid & 63;
    const int quad = lane >> 4, l15 = lane & 15;

    // Q B-frags for 2 strips of 16 q-rows (scale 0.125*log2e folded at rope)
    half8_t aq0[2], aq1[2];
#pragma unroll
    for (int s = 0; s < 2; ++s) {
        const _Float16* Qb = qh +
            ((size_t)(b * NH + h) * T_ + qt * 128 + w * 32 + s * 16 + l15) * 64 + quad * 8;
        aq0[s] = *(const half8_t*)(Qb);
        aq1[s] = *(const half8_t*)(Qb + 32);
    }

    const _Float16* Kb = kh  + (size_t)(b * NKV + hk) * (T_ * 64);
    const _Float16* Vb = vth + (size_t)(b * NKV + hk) * (64 * T_);

#define ATTN_STAGE(buf, ktile)                                                \
    {                                                                         \
        _Float16* kd = &Ks[buf][0];                                           \
        _Float16* vd = &Vs[buf][0];                                           \
        _Pragma("unroll")                                                     \
        for (int p = 0; p < 2; ++p) {                                         \
            int cb = p * 256 + w * 64;                                        \
            int c  = cb + lane;                                               \
            int l_ = c & 15, t_ = (c >> 4) & 3, g_ = c >> 6;                  \
            const _Float16* kg = Kb + ((size_t)((ktile) * 64 + t_ * 16 + l_)) * 64 + g_ * 8; \
            const _Float16* vg = Vb + ((size_t)(t_ * 16 + l_)) * T_ + (ktile) * 64 + g_ * 8; \
            async_copy16(kd + cb * 8, kg);                                    \
            async_copy16(vd + cb * 8, vg);                                    \
        }                                                                     \
    }

    float l_i[2] = {0.0f, 0.0f};
    f32x4 o_acc[2][4];
#pragma unroll
    for (int s = 0; s < 2; ++s)
#pragma unroll
        for (int dt = 0; dt < 4; ++dt) { f32x4 z = {0.f,0.f,0.f,0.f}; o_acc[s][dt] = z; }

    ATTN_STAGE(0, 0);
    __syncthreads();

    for (int kt = 0; kt < T_ / 64; ++kt) {
        const int cur = kt & 1;
        if (kt + 1 < T_ / 64) { ATTN_STAGE(cur ^ 1, kt + 1); }

        // K A-frags: chunk quad*64 + t*16 + l15 (d=8quad), +256 chunks d+32
        half8_t ak0[4], ak1[4];
#pragma unroll
        for (int t = 0; t < 4; ++t) {
            const _Float16* kr = &Ks[cur][(quad * 64 + t * 16 + l15) * 8];
            ak0[t] = *(const half8_t*)(kr);
            ak1[t] = *(const half8_t*)(kr + 2048);
        }
        // V A-frags: b128 per (t-pair u, dt): chunk (2*quad+u)*64 + dt*16 + l15
        half8_t av8[2][4];
#pragma unroll
        for (int u = 0; u < 2; ++u)
#pragma unroll
            for (int dt = 0; dt < 4; ++dt)
                av8[u][dt] = *(const half8_t*)&Vs[cur][((2 * quad + u) * 64 + dt * 16 + l15) * 8];

#pragma unroll
        for (int s = 0; s < 2; ++s) {
            f32x4 sv[4];
#pragma unroll
            for (int t = 0; t < 4; ++t) {
                f32x4 z = {0.f,0.f,0.f,0.f};
                z     = __builtin_amdgcn_mfma_f32_16x16x32_f16(ak0[t], aq0[s], z, 0, 0, 0);
                sv[t] = __builtin_amdgcn_mfma_f32_16x16x32_f16(ak1[t], aq1[s], z, 0, 0, 0);
            }
#pragma unroll
            for (int t = 0; t < 4; ++t) {
                float p0 = exp2f(sv[t][0]);
                float p1 = exp2f(sv[t][1]);
                float p2 = exp2f(sv[t][2]);
                float p3 = exp2f(sv[t][3]);
                l_i[s] += (p0 + p1) + (p2 + p3);
                half4_t pb;
                pb[0] = (_Float16)p0; pb[1] = (_Float16)p1;
                pb[2] = (_Float16)p2; pb[3] = (_Float16)p3;
                int u = t >> 1, hf = (t & 1) * 4;
#pragma unroll
                for (int dt = 0; dt < 4; ++dt) {
                    half4_t a4;
                    a4[0] = av8[u][dt][hf + 0];
                    a4[1] = av8[u][dt][hf + 1];
                    a4[2] = av8[u][dt][hf + 2];
                    a4[3] = av8[u][dt][hf + 3];
                    o_acc[s][dt] = __builtin_amdgcn_mfma_f32_16x16x16f16(
                        a4, pb, o_acc[s][dt], 0, 0, 0);
                }
            }
        }
        __syncthreads();
    }

    // epilogue: reduce l across quads (lane bits 4,5), normalize, write fp16
    // half4s into swizzled ctx chunks (O^T value at (quad,l15) =
    // (d = 16dt + 4quad + r, q)).
#pragma unroll
    for (int s = 0; s < 2; ++s) {
        float l = l_i[s];
        l += __shfl_xor(l, 16);
        l += __shfl_xor(l, 32);
        float inv = 1.0f / l;
        int t  = qt * 128 + w * 32 + s * 16 + l15;
        int m  = b * 2048 + t;
        int mb = m >> 7, ml = m & 127;
#pragma unroll
        for (int dt = 0; dt < 4; ++dt) {
            int d0 = 16 * dt + 4 * quad;          // 4-aligned; same k8 for r=0..3
            int kb = 2 * h + (d0 >> 5);
            int k8 = (d0 >> 3) & 3;
            half4_t hv;
            hv[0] = (_Float16)(o_acc[s][dt][0] * inv);
            hv[1] = (_Float16)(o_acc[s][dt][1] * inv);
            hv[2] = (_Float16)(o_acc[s][dt][2] * inv);
            hv[3] = (_Float16)(o_acc[s][dt][3] * inv);
            *(half4_t*)&ctx_h[(((size_t)(mb * 32 + kb) * 4 + k8) * 128 + ml) * 8
                              + 4 * (quad & 1)] = hv;
        }
    }
#undef ATTN_STAGE
}

// ---------------------------------------------------------------------------
extern "C" void kernel_launch(void* const* d_in, const int* in_sizes, int n_in,
                              void* d_out, int out_size, void* d_ws, size_t ws_size,
                              hipStream_t stream)
{
    const float* hs = (const float*)d_in[0];
    const float* Wq = (const float*)d_in[1];
    const float* bq = (const float*)d_in[2];
    const float* Wk = (const float*)d_in[3];
    const float* bk = (const float*)d_in[4];
    const float* Wv = (const float*)d_in[5];
    const float* bv = (const float*)d_in[6];
    const float* Wo = (const float*)d_in[7];
    const float* bo = (const float*)d_in[8];
    float* out = (float*)d_out;

    const size_t MB = 1024 * 1024;
    if (ws_size < 46 * MB) return;

    char* w = (char*)d_ws;
    _Float16* Whi  = (_Float16*)(w);             // 5 MB  [0,5)
    _Float16* Wlo  = (_Float16*)(w + 5 * MB);    // 5 MB  [5,10)
    float*    qf32 = (float*)(w + 10 * MB);      // 16 MB [10,26)
    float*    kf32 = (float*)(w + 26 * MB);      // 4 MB  [26,30)
    float*    vf32 = (float*)(w + 30 * MB);      // 4 MB  [30,34)
    _Float16* qh   = (_Float16*)(w + 34 * MB);   // 8 MB  [34,42)
    _Float16* kh   = (_Float16*)(w + 42 * MB);   // 2 MB  [42,44)
    _Float16* vth  = (_Float16*)(w + 44 * MB);   // 2 MB  [44,46)
    // aliases (lifetimes disjoint):
    _Float16* hs_h  = qh;                        // dead once rope writes qh
    float2*   tab   = (float2*)vth;              // dead once vtrans writes vth
    _Float16* ctx_h = (_Float16*)(w + 10 * MB);  // [10,18): qf32 dead after rope

    tab_kernel<<<256, 256, 0, stream>>>(tab);
    prep_w_kernel<<<1280, 256, 0, stream>>>(Wq, Wk, Wv, Wo, Whi, Wlo);
    prep_a_kernel<<<2048, 256, 0, stream>>>(hs, hs_h);
    gemm2p_kernel<0><<<dim3(24, 32), 128, 0, stream>>>(
        hs_h, Whi, Wlo, 0, bq, bk, bv, qf32, kf32, vf32);
    rope_half_kernel<<<(B_ * (NH + NKV) * T_ * 32) / 256, 256, 0, stream>>>(
        qf32, kf32, tab, qh, kh);
    vtrans_kernel<<<dim3(T_ / 64, B_ * NKV), 256, 0, stream>>>(vf32, vth);
    attn_kernel<<<dim3(16, 32), 256, 0, stream>>>(qh, kh, vth, ctx_h);
    gemm2p_kernel<1><<<dim3(16, 32), 128, 0, stream>>>(
        ctx_h, Whi, Wlo, 12, bo, nullptr, nullptr, out, nullptr, nullptr);
}

// Round 11
// 252.369 us; speedup vs baseline: 1.2169x; 1.0095x over previous
//
#include <hip/hip_runtime.h>
#include <math.h>

// GQA block. Round 11: r10 base; attention VALU fixes: (a) PV A-frags via
// __builtin_shufflevector register-pair selection (no element extraction),
// (b) l computed by ones-MFMA row-sum (no VALU adds, no epilogue shuffles).
// B=2,T=2048,DIM=1024,H=16,HKV=4,HD=64.

#define B_   2
#define T_   2048
#define DIM_ 1024
#define NH   16
#define NKV  4
#define HD_  64
#define BT_  (B_ * T_)

typedef _Float16 half8_t __attribute__((ext_vector_type(8)));
typedef _Float16 half4_t __attribute__((ext_vector_type(4)));
typedef float    f32x4   __attribute__((ext_vector_type(4)));

__device__ __forceinline__ void async_copy16(_Float16* lds, const _Float16* g) {
    __builtin_amdgcn_global_load_lds(
        (const __attribute__((address_space(1))) void*)g,
        (__attribute__((address_space(3))) void*)lds, 16, 0, 0);
}

// ---------------------------------------------------------------------------
// Kernel 0: RoPE sincos table: tab[t*32+i] = (cos, sin)(t * 10000^(-i/32))
// ---------------------------------------------------------------------------
__global__ __launch_bounds__(256) void tab_kernel(float2* __restrict__ tab)
{
    int gid = blockIdx.x * 256 + threadIdx.x;   // 0..65535
    int t = gid >> 5, i = gid & 31;
    double invf = pow(10000.0, -(double)i / 32.0);
    double ang  = (double)t * invf;
    tab[gid] = make_float2((float)cos(ang), (float)sin(ang));
}

// ---------------------------------------------------------------------------
// Kernel 1: weight prep (validated r3-r10). fp32 W rows (2560: Wq|Wk|Wv|Wo) ->
// fp16 hi/lo planes, MFMA-fragment-swizzled chunks:
// c = ((nb*32+kb)*4 + k8)*128 + nl  holds  W[nb*128+nl][kb*32+k8*8 .. +8]
// ---------------------------------------------------------------------------
__global__ __launch_bounds__(256) void prep_w_kernel(
    const float* __restrict__ Wq, const float* __restrict__ Wk,
    const float* __restrict__ Wv, const float* __restrict__ Wo,
    _Float16* __restrict__ Whi, _Float16* __restrict__ Wlo)
{
    int c = blockIdx.x * 256 + threadIdx.x;       // 0..327679
    int nl = c & 127, k8 = (c >> 7) & 3, kb = (c >> 9) & 31, nb = c >> 14;
    int n = nb * 128 + nl, k = kb * 32 + k8 * 8;
    const float* src;
    if (n < 1024)      src = Wq + (size_t)n * 1024;
    else if (n < 1280) src = Wk + (size_t)(n - 1024) * 1024;
    else if (n < 1536) src = Wv + (size_t)(n - 1280) * 1024;
    else               src = Wo + (size_t)(n - 1536) * 1024;
    float4 f0 = *(const float4*)(src + k);
    float4 f1 = *(const float4*)(src + k + 4);
    float xs[8] = {f0.x, f0.y, f0.z, f0.w, f1.x, f1.y, f1.z, f1.w};
    half8_t hi, lo;
#pragma unroll
    for (int j = 0; j < 8; ++j) {
        _Float16 h = (_Float16)xs[j];
        hi[j] = h;
        lo[j] = (_Float16)(xs[j] - (float)h);
    }
    *(half8_t*)&Whi[(size_t)c * 8] = hi;
    *(half8_t*)&Wlo[(size_t)c * 8] = lo;
}

// ---------------------------------------------------------------------------
// Kernel 2: A prep: hs fp32 [4096 x 1024] -> fp16 swizzled chunks
// [mb][kb][k8][ml]*8.
// ---------------------------------------------------------------------------
__global__ __launch_bounds__(256) void prep_a_kernel(
    const float* __restrict__ hs, _Float16* __restrict__ Ah)
{
    int gid = blockIdx.x * 256 + threadIdx.x;    // 0..524287
    int k8 = gid & 3, kb = (gid >> 2) & 31, ml = (gid >> 7) & 127, mb = gid >> 14;
    const float* src = hs + (size_t)(mb * 128 + ml) * 1024 + kb * 32 + k8 * 8;
    float4 f0 = *(const float4*)src;
    float4 f1 = *(const float4*)(src + 4);
    half8_t hv;
    hv[0] = (_Float16)f0.x; hv[1] = (_Float16)f0.y;
    hv[2] = (_Float16)f0.z; hv[3] = (_Float16)f0.w;
    hv[4] = (_Float16)f1.x; hv[5] = (_Float16)f1.y;
    hv[6] = (_Float16)f1.z; hv[7] = (_Float16)f1.w;
    size_t c = ((size_t)(mb * 32 + kb) * 4 + k8) * 128 + ml;
    *(half8_t*)&Ah[c * 8] = hv;
}

// ---------------------------------------------------------------------------
// Kernel 3: 2-pass MFMA GEMM (r10, validated). Tile 128x64, BK=32, 128 thr =
// 2 waves (each 64x64), all-DMA dbuf staging.
// MODE 0: QKV epilogue (each N-tile = one head). MODE 1: row-major.
// ---------------------------------------------------------------------------
template <int MODE>
__global__ __launch_bounds__(128, 2) void gemm2p_kernel(
    const _Float16* __restrict__ Ah,
    const _Float16* __restrict__ Whi, const _Float16* __restrict__ Wlo,
    int nb0,
    const float* __restrict__ bq, const float* __restrict__ bk,
    const float* __restrict__ bv,
    float* __restrict__ o0, float* __restrict__ o1, float* __restrict__ o2)
{
    __shared__ _Float16 sA [2][4096];
    __shared__ _Float16 sBh[2][2048];
    __shared__ _Float16 sBl[2][2048];

    const int tid  = threadIdx.x;       // 0..127
    const int w    = tid >> 6, lane = tid & 63;
    const int quad = lane >> 4, l15 = lane & 15;
    const int mb   = blockIdx.y;
    const int nblk = blockIdx.x;
    const int hb64 = (nblk & 1) * 64;

    const _Float16* AB   = Ah  + (size_t)mb * 32 * 4096;
    const _Float16* WhiB = Whi + (size_t)(nb0 + (nblk >> 1)) * 32 * 4096;
    const _Float16* WloB = Wlo + (size_t)(nb0 + (nblk >> 1)) * 32 * 4096;

    f32x4 acc[4][4];
#pragma unroll
    for (int mt = 0; mt < 4; ++mt)
#pragma unroll
        for (int nt = 0; nt < 4; ++nt) {
            f32x4 z = {0.f, 0.f, 0.f, 0.f};
            acc[mt][nt] = z;
        }

#define GEMM_STAGE(buf, kbl)                                                  \
    {                                                                         \
        const _Float16* ga = AB   + (size_t)(kbl) * 4096;                     \
        const _Float16* gh = WhiB + (size_t)(kbl) * 4096;                     \
        const _Float16* gl = WloB + (size_t)(kbl) * 4096;                     \
        _Pragma("unroll")                                                     \
        for (int p = 0; p < 4; ++p) {                                         \
            int cb = p * 128 + w * 64;                                        \
            async_copy16(&sA[buf][cb * 8], ga + (size_t)(cb + lane) * 8);     \
        }                                                                     \
        _Pragma("unroll")                                                     \
        for (int p = 0; p < 2; ++p) {                                         \
            int cb = p * 128 + w * 64;                                        \
            int g  = (cb >> 6) * 128 + hb64 + lane;                           \
            async_copy16(&sBh[buf][cb * 8], gh + (size_t)g * 8);              \
            async_copy16(&sBl[buf][cb * 8], gl + (size_t)g * 8);              \
        }                                                                     \
    }

    GEMM_STAGE(0, 0);
    __syncthreads();

    for (int kb = 0; kb < 32; ++kb) {
        const int cur = kb & 1;
        if (kb + 1 < 32) { GEMM_STAGE(cur ^ 1, kb + 1); }

        half8_t af[4], bf[4], blv[4];
#pragma unroll
        for (int mt = 0; mt < 4; ++mt) {
            int ch = quad * 128 + w * 64 + mt * 16 + l15;
            af[mt] = *(const half8_t*)&sA[cur][ch * 8];
        }
#pragma unroll
        for (int nt = 0; nt < 4; ++nt) {
            int ch = quad * 64 + nt * 16 + l15;
            bf[nt]  = *(const half8_t*)&sBh[cur][ch * 8];
            blv[nt] = *(const half8_t*)&sBl[cur][ch * 8];
        }
#pragma unroll
        for (int mt = 0; mt < 4; ++mt)
#pragma unroll
            for (int nt = 0; nt < 4; ++nt) {
                acc[mt][nt] = __builtin_amdgcn_mfma_f32_16x16x32_f16(af[mt], bf[nt],  acc[mt][nt], 0, 0, 0);
                acc[mt][nt] = __builtin_amdgcn_mfma_f32_16x16x32_f16(af[mt], blv[nt], acc[mt][nt], 0, 0, 0);
            }
        __syncthreads();
    }

    const int m0 = mb * 128 + w * 64;
    if constexpr (MODE == 0) {
        const float* bias; float* outp; int nh2, hh;
        if (nblk < 16)      { bias = bq; outp = o0; nh2 = NH;  hh = nblk; }
        else if (nblk < 20) { bias = bk; outp = o1; nh2 = NKV; hh = nblk - 16; }
        else                { bias = bv; outp = o2; nh2 = NKV; hh = nblk - 20; }
#pragma unroll
        for (int mt = 0; mt < 4; ++mt)
#pragma unroll
            for (int r = 0; r < 4; ++r) {
                int m  = m0 + mt * 16 + quad * 4 + r;
                int b_ = m >> 11, t_ = m & 2047;
                float* cp = outp + (((size_t)(b_ * nh2 + hh)) * T_ + t_) * 64;
#pragma unroll
                for (int nt = 0; nt < 4; ++nt) {
                    int dd = nt * 16 + l15;
                    cp[dd] = acc[mt][nt][r] + bias[hh * 64 + dd];
                }
            }
    } else {
        int n0 = nblk * 64;
#pragma unroll
        for (int mt = 0; mt < 4; ++mt)
#pragma unroll
            for (int r = 0; r < 4; ++r) {
                int m = m0 + mt * 16 + quad * 4 + r;
#pragma unroll
                for (int nt = 0; nt < 4; ++nt) {
                    int n = n0 + nt * 16 + l15;
                    o0[(size_t)m * 1024 + n] = acc[mt][nt][r] + bq[n];
                }
            }
    }
#undef GEMM_STAGE
}

// ---------------------------------------------------------------------------
// Kernel 4: RoPE via table, fp32 -> fp16. q scaled by 0.125*log2(e) so the
// softmax can use exp2 directly.
// ---------------------------------------------------------------------------
__global__ __launch_bounds__(256) void rope_half_kernel(
    const float* __restrict__ qf, const float* __restrict__ kf,
    const float2* __restrict__ tab,
    _Float16* __restrict__ qh, _Float16* __restrict__ kh)
{
    int gid = blockIdx.x * 256 + threadIdx.x;
    int i   = gid & 31;
    int row = gid >> 5;
    const float* src; _Float16* dst; int t; float sc;
    if (row < B_ * NH * T_) {
        src = qf + (size_t)row * 64; dst = qh + (size_t)row * 64;
        t = row & (T_ - 1); sc = 0.125f * 1.44269504088896f;
    } else {
        int r = row - B_ * NH * T_;
        src = kf + (size_t)r * 64; dst = kh + (size_t)r * 64;
        t = r & (T_ - 1); sc = 1.0f;
    }
    float2 cs = tab[t * 32 + i];
    float c = cs.x, s = cs.y;
    float x0 = src[i], x1 = src[i + 32];
    float xe = src[2 * i], xo = src[2 * i + 1];
    dst[i]      = (_Float16)((x0 * c - xo * s) * sc);
    dst[i + 32] = (_Float16)((x1 * c + xe * s) * sc);
}

// ---------------------------------------------------------------------------
// Kernel 5: V transpose fp32 [b,hkv,t,d] -> fp16 [b,hkv,d,t'] with keys
// PERMUTED within each 64-key group (r7/r10, validated, 0 bank conflicts):
// original k = 16t+4q+j stored at p = q*16 + t*4 + j.
// ---------------------------------------------------------------------------
__global__ __launch_bounds__(256) void vtrans_kernel(
    const float* __restrict__ vf, _Float16* __restrict__ vth)
{
    __shared__ float ts[64][65];
    const int bhk = blockIdx.y;
    const int t0  = blockIdx.x * 64;
    const int tid = threadIdx.x;
    const float* src = vf + (size_t)bhk * T_ * 64 + (size_t)t0 * 64;

    int row = tid >> 2, c0 = (tid & 3) * 16;
#pragma unroll
    for (int j = 0; j < 16; ++j)
        ts[row][c0 + j] = src[(size_t)row * 64 + c0 + j];
    __syncthreads();

    int drow = tid >> 2;                  // d index 0..63
    int t4   = (c0 >> 4) * 4;             // t = c0/16
    _Float16* dstb = vth + (size_t)bhk * 64 * T_ + (size_t)drow * T_ + t0;
#pragma unroll
    for (int q = 0; q < 4; ++q) {
        half4_t hv;
#pragma unroll
        for (int j = 0; j < 4; ++j)
            hv[j] = (_Float16)ts[c0 + q * 4 + j][drow];
        *(half4_t*)&dstb[q * 16 + t4] = hv;
    }
}

// ---------------------------------------------------------------------------
// Kernel 6: flash attention. 128q/block, 256 threads, 4 waves x 32q, full
// 32-iter k-loop. S^T = K Q^T -> exp2 -> P register-direct into 16x16x16 PV
// MFMAs; PV A-frags selected from b128 loads via shufflevector (reg pairs,
// no VALU). l accumulated by ones-MFMA row sums (no adds, no shuffles).
// K LDS chunk g*64 + t*16 + l  <-> K[key=16t+l][d=8g..+8]
// V LDS chunk g*64 + dt*16 + l <-> V^T[d=16dt+l][perm-pos 8g..+8]
// ---------------------------------------------------------------------------
__global__ __launch_bounds__(256, 2) void attn_kernel(
    const _Float16* __restrict__ qh, const _Float16* __restrict__ kh,
    const _Float16* __restrict__ vth, _Float16* __restrict__ ctx_h)
{
    __shared__ _Float16 Ks[2][4096];
    __shared__ _Float16 Vs[2][4096];

    const int qt = blockIdx.x;          // 0..15 (128-q tiles)
    const int bh = blockIdx.y;          // 0..31
    const int b  = bh >> 4, h = bh & 15, hk = h >> 2;
    const int tid  = threadIdx.x;
    const int w    = tid >> 6;
    const int lane = tid & 63;
    const int quad = lane >> 4, l15 = lane & 15;

    // Q B-frags for 2 strips of 16 q-rows (scale 0.125*log2e folded at rope)
    half8_t aq0[2], aq1[2];
#pragma unroll
    for (int s = 0; s < 2; ++s) {
        const _Float16* Qb = qh +
            ((size_t)(b * NH + h) * T_ + qt * 128 + w * 32 + s * 16 + l15) * 64 + quad * 8;
        aq0[s] = *(const half8_t*)(Qb);
        aq1[s] = *(const half8_t*)(Qb + 32);
    }

    const _Float16* Kb = kh  + (size_t)(b * NKV + hk) * (T_ * 64);
    const _Float16* Vb = vth + (size_t)(b * NKV + hk) * (64 * T_);

#define ATTN_STAGE(buf, ktile)                                                \
    {                                                                         \
        _Float16* kd = &Ks[buf][0];                                           \
        _Float16* vd = &Vs[buf][0];                                           \
        _Pragma("unroll")                                                     \
        for (int p = 0; p < 2; ++p) {                                         \
            int cb = p * 256 + w * 64;                                        \
            int c  = cb + lane;                                               \
            int l_ = c & 15, t_ = (c >> 4) & 3, g_ = c >> 6;                  \
            const _Float16* kg = Kb + ((size_t)((ktile) * 64 + t_ * 16 + l_)) * 64 + g_ * 8; \
            const _Float16* vg = Vb + ((size_t)(t_ * 16 + l_)) * T_ + (ktile) * 64 + g_ * 8; \
            async_copy16(kd + cb * 8, kg);                                    \
            async_copy16(vd + cb * 8, vg);                                    \
        }                                                                     \
    }

    const half4_t ones = {(_Float16)1.0f, (_Float16)1.0f,
                          (_Float16)1.0f, (_Float16)1.0f};
    f32x4 l_acc[2];
    f32x4 o_acc[2][4];
#pragma unroll
    for (int s = 0; s < 2; ++s) {
        f32x4 z = {0.f, 0.f, 0.f, 0.f};
        l_acc[s] = z;
#pragma unroll
        for (int dt = 0; dt < 4; ++dt) o_acc[s][dt] = z;
    }

    ATTN_STAGE(0, 0);
    __syncthreads();

    for (int kt = 0; kt < T_ / 64; ++kt) {
        const int cur = kt & 1;
        if (kt + 1 < T_ / 64) { ATTN_STAGE(cur ^ 1, kt + 1); }

        // K A-frags: chunk quad*64 + t*16 + l15 (d=8quad), +256 chunks d+32
        half8_t ak0[4], ak1[4];
#pragma unroll
        for (int t = 0; t < 4; ++t) {
            const _Float16* kr = &Ks[cur][(quad * 64 + t * 16 + l15) * 8];
            ak0[t] = *(const half8_t*)(kr);
            ak1[t] = *(const half8_t*)(kr + 2048);
        }
        // V A-frags: b128 per (t-pair u, dt): chunk (2*quad+u)*64 + dt*16 + l15
        half8_t av8[2][4];
#pragma unroll
        for (int u = 0; u < 2; ++u)
#pragma unroll
            for (int dt = 0; dt < 4; ++dt)
                av8[u][dt] = *(const half8_t*)&Vs[cur][((2 * quad + u) * 64 + dt * 16 + l15) * 8];

#pragma unroll
        for (int s = 0; s < 2; ++s) {
            f32x4 sv[4];
#pragma unroll
            for (int t = 0; t < 4; ++t) {
                f32x4 z = {0.f,0.f,0.f,0.f};
                z     = __builtin_amdgcn_mfma_f32_16x16x32_f16(ak0[t], aq0[s], z, 0, 0, 0);
                sv[t] = __builtin_amdgcn_mfma_f32_16x16x32_f16(ak1[t], aq1[s], z, 0, 0, 0);
            }
#pragma unroll
            for (int t = 0; t < 4; ++t) {
                float p0 = exp2f(sv[t][0]);
                float p1 = exp2f(sv[t][1]);
                float p2 = exp2f(sv[t][2]);
                float p3 = exp2f(sv[t][3]);
                half4_t pb;
                pb[0] = (_Float16)p0; pb[1] = (_Float16)p1;
                pb[2] = (_Float16)p2; pb[3] = (_Float16)p3;
                // l row-sum via ones-MFMA: C[m][q] += sum_k P[k][q]
                l_acc[s] = __builtin_amdgcn_mfma_f32_16x16x16f16(
                    ones, pb, l_acc[s], 0, 0, 0);
                int u = t >> 1;
#pragma unroll
                for (int dt = 0; dt < 4; ++dt) {
                    half4_t a4 = (t & 1)
                        ? __builtin_shufflevector(av8[u][dt], av8[u][dt], 4, 5, 6, 7)
                        : __builtin_shufflevector(av8[u][dt], av8[u][dt], 0, 1, 2, 3);
                    o_acc[s][dt] = __builtin_amdgcn_mfma_f32_16x16x16f16(
                        a4, pb, o_acc[s][dt], 0, 0, 0);
                }
            }
        }
        __syncthreads();
    }

    // epilogue: l complete per lane (all rows of l_acc equal); normalize and
    // write fp16 half4s into swizzled ctx chunks
    // (O^T value at (quad,l15) = (d = 16dt + 4quad + r, q)).
#pragma unroll
    for (int s = 0; s < 2; ++s) {
        float inv = 1.0f / l_acc[s][0];
        int t  = qt * 128 + w * 32 + s * 16 + l15;
        int m  = b * 2048 + t;
        int mb = m >> 7, ml = m & 127;
#pragma unroll
        for (int dt = 0; dt < 4; ++dt) {
            int d0 = 16 * dt + 4 * quad;          // 4-aligned; same k8 for r=0..3
            int kb = 2 * h + (d0 >> 5);
            int k8 = (d0 >> 3) & 3;
            half4_t hv;
            hv[0] = (_Float16)(o_acc[s][dt][0] * inv);
            hv[1] = (_Float16)(o_acc[s][dt][1] * inv);
            hv[2] = (_Float16)(o_acc[s][dt][2] * inv);
            hv[3] = (_Float16)(o_acc[s][dt][3] * inv);
            *(half4_t*)&ctx_h[(((size_t)(mb * 32 + kb) * 4 + k8) * 128 + ml) * 8
                              + 4 * (quad & 1)] = hv;
        }
    }
#undef ATTN_STAGE
}

// ---------------------------------------------------------------------------
extern "C" void kernel_launch(void* const* d_in, const int* in_sizes, int n_in,
                              void* d_out, int out_size, void* d_ws, size_t ws_size,
                              hipStream_t stream)
{
    const float* hs = (const float*)d_in[0];
    const float* Wq = (const float*)d_in[1];
    const float* bq = (const float*)d_in[2];
    const float* Wk = (const float*)d_in[3];
    const float* bk = (const float*)d_in[4];
    const float* Wv = (const float*)d_in[5];
    const float* bv = (const float*)d_in[6];
    const float* Wo = (const float*)d_in[7];
    const float* bo = (const float*)d_in[8];
    float* out = (float*)d_out;

    const size_t MB = 1024 * 1024;
    if (ws_size < 46 * MB) return;

    char* w = (char*)d_ws;
    _Float16* Whi  = (_Float16*)(w);             // 5 MB  [0,5)
    _Float16* Wlo  = (_Float16*)(w + 5 * MB);    // 5 MB  [5,10)
    float*    qf32 = (float*)(w + 10 * MB);      // 16 MB [10,26)
    float*    kf32 = (float*)(w + 26 * MB);      // 4 MB  [26,30)
    float*    vf32 = (float*)(w + 30 * MB);      // 4 MB  [30,34)
    _Float16* qh   = (_Float16*)(w + 34 * MB);   // 8 MB  [34,42)
    _Float16* kh   = (_Float16*)(w + 42 * MB);   // 2 MB  [42,44)
    _Float16* vth  = (_Float16*)(w + 44 * MB);   // 2 MB  [44,46)
    // aliases (lifetimes disjoint):
    _Float16* hs_h  = qh;                        // dead once rope writes qh
    float2*   tab   = (float2*)vth;              // dead once vtrans writes vth
    _Float16* ctx_h = (_Float16*)(w + 10 * MB);  // [10,18): qf32 dead after rope

    tab_kernel<<<256, 256, 0, stream>>>(tab);
    prep_w_kernel<<<1280, 256, 0, stream>>>(Wq, Wk, Wv, Wo, Whi, Wlo);
    prep_a_kernel<<<2048, 256, 0, stream>>>(hs, hs_h);
    gemm2p_kernel<0><<<dim3(24, 32), 128, 0, stream>>>(
        hs_h, Whi, Wlo, 0, bq, bk, bv, qf32, kf32, vf32);
    rope_half_kernel<<<(B_ * (NH + NKV) * T_ * 32) / 256, 256, 0, stream>>>(
        qf32, kf32, tab, qh, kh);
    vtrans_kernel<<<dim3(T_ / 64, B_ * NKV), 256, 0, stream>>>(vf32, vth);
    attn_kernel<<<dim3(16, 32), 256, 0, stream>>>(qh, kh, vth, ctx_h);
    gemm2p_kernel<1><<<dim3(16, 32), 128, 0, stream>>>(
        ctx_h, Whi, Wlo, 12, bo, nullptr, nullptr, out, nullptr, nullptr);
}